// Round 10
// baseline (336.729 us; speedup 1.0000x reference)
//
#include <hip/hip_runtime.h>

// Problem constants (match reference)
#define VOCABN 100
#define EMBEDN 16
#define STATEN 7
#define OUTN   10
#define BATCHN 4096
#define SEQT   512
#define L2E 1.44269504088896340736f

__device__ __forceinline__ float fexp2(float x){ float r; asm("v_exp_f32 %0, %1":"=v"(r):"v"(x)); return r; }
__device__ __forceinline__ float frcp (float x){ float r; asm("v_rcp_f32 %0, %1":"=v"(r):"v"(x)); return r; }

// DPP helpers. row_ror:n = 0x120+n (16-lane ring, parity-preserving for even n);
// quad_perm [1,0,3,2] = 0xB1 (parity-partner exchange).
template<int C> __device__ __forceinline__ int dppi(int x){
  return __builtin_amdgcn_update_dpp(0, x, C, 0xF, 0xF, true);
}
template<int C> __device__ __forceinline__ float dppf(float x){
  return __int_as_float(__builtin_amdgcn_update_dpp(0, __float_as_int(x), C, 0xF, 0xF, true));
}

// ---------------------------------------------------------------------------
// Kernel A (round-3 version): embW2[v][pos] = pre-scaled gate pre-activations,
// pos = s*2+p; p0 -> (i,f), p1 -> (g,o). Scales i,f,o: -L2E; g: +2L2E.
// ---------------------------------------------------------------------------
__global__ void embw_kernel(const float* __restrict__ emb, const float* __restrict__ W,
                            const float* __restrict__ b, float* __restrict__ embw){
  int v = blockIdx.x, j = threadIdx.x;          // j 0..31
  int pos = j >> 1, g2 = j & 1;
  int s = pos >> 1, p = pos & 1, gate = p*2 + g2;
  float val = 0.0f;
  if (s < STATEN) {
    int col = gate*STATEN + s;
    val = b[col];
    #pragma unroll
    for (int e = 0; e < EMBEDN; ++e) val = fmaf(emb[v*EMBEDN+e], W[e*28+col], val);
    val *= (gate == 2) ? (2.0f*L2E) : (-L2E);
  }
  embw[v*32 + pos*2 + g2] = val;
}

// ---------------------------------------------------------------------------
// ABLATION TEMPLATE on the round-3 structure (1024 blocks x 64 thr, 4 chains
// of 16 lanes each). V selects which stage is deleted:
//   V0: control — EXACT round-3 datapath (real output, launched last)
//   V1: no LDS reads in loop (pf const)        -> LDS/lgkmcnt share
//   V2: no transcendentals (fma+clamp gates)   -> trans share
//   V3: no capture/flush                       -> flush share
//   V4: skeleton (no z-tree, no trans, no LDS) -> loop-structure floor
// V1..V4 write bounded garbage; V0 overwrites every output element.
// ---------------------------------------------------------------------------
template<int V>
__global__ void __launch_bounds__(64,1)
lstm_ab(const int* __restrict__ tokens, const float* __restrict__ embw,
        const float* __restrict__ U, const float* __restrict__ Wd,
        const float* __restrict__ bdv, float* __restrict__ out){
  constexpr bool LDSQ  = (V==0)||(V==2)||(V==3);  // in-loop LDS prefetch
  constexpr bool TRANS = (V==0)||(V==1)||(V==3);  // real trans gates
  constexpr bool FLUSH = (V!=3);                  // capture + staged flush
  constexpr bool ZTREE = (V!=4);                  // full h@U tree

  __shared__ float embW_s[VOCABN*32];   // 12.8 KB
  __shared__ int   tok_s[4*520];        // 4 chains (+pads for over-read)

  const int L = threadIdx.x;
  const int b0 = blockIdx.x*4;

  for (int i=L;i<VOCABN*8;i+=64) ((float4*)embW_s)[i]=((const float4*)embw)[i];
  for (int i=L;i<512;i+=64){ int r=i>>7,c4=i&127;
    int4 v=((const int4*)(tokens+(size_t)(b0+r)*SEQT))[c4];
    *((int4*)&tok_s[r*520+c4*4])=v; }
  if (L<4){ tok_s[L*520+512]=0; tok_s[L*520+513]=0; tok_s[L*520+514]=0; }
  __syncthreads();

  const int pos=L&15, ch=L>>4, s=pos>>1, p=pos&1;

  // sigma discovery: run own state id through the exact broadcast net
  int sg[8];
  sg[0]=s;
  sg[1]=dppi<0x122>(s); sg[2]=dppi<0x124>(s); sg[3]=dppi<0x126>(s);
  sg[4]=dppi<0x128>(s); sg[5]=dppi<0x12A>(s); sg[6]=dppi<0x12C>(s); sg[7]=dppi<0x12E>(s);

  // recurrent weights, pre-permuted by sigma, pre-scaled per gate
  float Uc0[8], Uc1[8];
  {
    const int gA=p*2, gB=p*2+1;
    const float sA = (gA==2)?(2.0f*L2E):(-L2E);
    const float sB = (gB==2)?(2.0f*L2E):(-L2E);
    #pragma unroll
    for (int k=0;k<8;++k){
      int sk=sg[k]; bool vld=(sk<STATEN)&&(s<STATEN);
      Uc0[k]= vld ? U[sk*28+gA*7+s]*sA : 0.0f;
      Uc1[k]= vld ? U[sk*28+gB*7+s]*sB : 0.0f;
    }
  }
  // dense weights (half per parity), pre-permuted, pre-scaled by log2e
  float Wdc[8][5], bdr[5];
  #pragma unroll
  for (int k=0;k<8;++k){ int sk=sg[k];
    #pragma unroll
    for (int o=0;o<5;++o) Wdc[k][o] = (sk<STATEN)? Wd[sk*10+p*5+o]*L2E : 0.0f; }
  #pragma unroll
  for (int o=0;o<5;++o) bdr[o]=bdv[p*5+o]*L2E;

  const int* trow=&tok_s[ch*520];
  float* outp = out + ((size_t)(b0+ch)*SEQT + s)*OUTN + p*5;

  float hh[8], hc[8], lg[5], ee[5];
  #pragma unroll
  for (int k=0;k<8;++k){ hh[k]=0.0f; hc[k]=0.0f; }
  #pragma unroll
  for (int o=0;o<5;++o){ lg[o]=0.0f; ee[o]=0.0f; }
  float mx=0.0f, rs=0.0f;

  // prefetch queues (V0/V2/V3); constant pf for V1/V4
  int tk2 = 0;
  float2 pf0, pf1;
  if constexpr (LDSQ){
    tk2 = trow[2];
    pf0 = *(const float2*)&embW_s[trow[0]*32+pos*2];
    pf1 = *(const float2*)&embW_s[trow[1]*32+pos*2];
  } else {
    pf0 = *(const float2*)&embW_s[pos*2];   // fixed row 0
    pf1 = pf0;
  }
  float Cc=0.0f, h=0.0f;

  for (int t8=0;t8<SEQT;t8+=8){
    #pragma unroll
    for (int u=0;u<8;++u){
      float2 pf2; int tk3;
      if constexpr (LDSQ){
        pf2 = *(const float2*)&embW_s[tk2*32+pos*2];
        tk3 = trow[t8+u+3];
      }

      // broadcast h_{t-1} across the 16-lane chain (depth-1 DPP net)
      float r0=h;
      float r1=dppf<0x122>(h), r2=dppf<0x124>(h), r3=dppf<0x126>(h);
      float r4=dppf<0x128>(h), r5=dppf<0x12A>(h), r6=dppf<0x12C>(h), r7=dppf<0x12E>(h);

      if constexpr (FLUSH){
        // lane-pair of state s captures h of timestep t-1 when u==s+1 (mod 8)
        bool cap = (s==((u+7)&7));
        hh[0]=cap?r0:hh[0]; hh[1]=cap?r1:hh[1]; hh[2]=cap?r2:hh[2]; hh[3]=cap?r3:hh[3];
        hh[4]=cap?r4:hh[4]; hh[5]=cap?r5:hh[5]; hh[6]=cap?r6:hh[6]; hh[7]=cap?r7:hh[7];

        // branch-free staged flush of the PREVIOUS octet
        if (u==0){ hc[0]=hh[0];hc[1]=hh[1];hc[2]=hh[2];hc[3]=hh[3];
                   hc[4]=hh[4];hc[5]=hh[5];hc[6]=hh[6];hc[7]=hh[7]; }
        if (u==1){
          float a0=bdr[0], a1=bdr[1];
          #pragma unroll
          for (int k=0;k<8;++k){ a0=__builtin_fmaf(hc[k],Wdc[k][0],a0);
                                 a1=__builtin_fmaf(hc[k],Wdc[k][1],a1); }
          lg[0]=a0; lg[1]=a1; }
        if (u==2){
          float a2=bdr[2], a3=bdr[3];
          #pragma unroll
          for (int k=0;k<8;++k){ a2=__builtin_fmaf(hc[k],Wdc[k][2],a2);
                                 a3=__builtin_fmaf(hc[k],Wdc[k][3],a3); }
          lg[2]=a2; lg[3]=a3; }
        if (u==3){
          float a4=bdr[4];
          #pragma unroll
          for (int k=0;k<8;++k) a4=__builtin_fmaf(hc[k],Wdc[k][4],a4);
          lg[4]=a4; }
        if (u==4){
          float m=fmaxf(fmaxf(fmaxf(lg[0],lg[1]),fmaxf(lg[2],lg[3])),lg[4]);
          mx=fmaxf(m, dppf<0xB1>(m)); }
        if (u==5){
          ee[0]=fexp2(lg[0]-mx); ee[1]=fexp2(lg[1]-mx); ee[2]=fexp2(lg[2]-mx);
          ee[3]=fexp2(lg[3]-mx); ee[4]=fexp2(lg[4]-mx); }
        if (u==6){
          float sm=((ee[0]+ee[1])+(ee[2]+ee[3]))+ee[4];
          rs=frcp(sm + dppf<0xB1>(sm)); }
        if (u==7){
          if (t8>0){
            outp[0]=ee[0]*rs; outp[1]=ee[1]*rs; outp[2]=ee[2]*rs;
            outp[3]=ee[3]*rs; outp[4]=ee[4]*rs;
            outp += 8*OUTN;
          } }
      }

      // ---- z = embW'[tok] + h @ U' (tree-sum, pre-scaled) ----
      float zA, zB;
      if constexpr (ZTREE){
        { float q0=__builtin_fmaf(r0,Uc0[0],pf0.x);
          float q1=__builtin_fmaf(r1,Uc0[1], r2*Uc0[2]);
          float q2=__builtin_fmaf(r3,Uc0[3], r4*Uc0[4]);
          float q3=__builtin_fmaf(r5,Uc0[5], r6*Uc0[6]);
          zA=(q0+q1)+((q2+q3)+r7*Uc0[7]); }
        { float q0=__builtin_fmaf(r0,Uc1[0],pf0.y);
          float q1=__builtin_fmaf(r1,Uc1[1], r2*Uc1[2]);
          float q2=__builtin_fmaf(r3,Uc1[3], r4*Uc1[4]);
          float q3=__builtin_fmaf(r5,Uc1[5], r6*Uc1[6]);
          zB=(q0+q1)+((q2+q3)+r7*Uc1[7]); }
      } else {
        zA = __builtin_fmaf(r0, 0.0625f, pf0.x);
        zB = __builtin_fmaf(r7, 0.0625f, pf0.y);
      }

      // gates: p0: gA=i, gB=f ; p1: gA=rcp-part of g, gB=o
      float gA, gB;
      if constexpr (TRANS){
        gA=frcp(1.0f+fexp2(zA));
        gB=frcp(1.0f+fexp2(zB));
      } else {
        gA=fminf(fmaxf(__builtin_fmaf(zA,-0.25f,0.5f),0.0f),1.0f);
        gB=fminf(fmaxf(__builtin_fmaf(zB,-0.25f,0.5f),0.0f),1.0f);
      }
      float gg_s=__builtin_fmaf(gA,-4.0f*L2E,2.0f*L2E); // 2L2E*tanh(zg) on p1
      float gg_x=dppf<0xB1>(gg_s);                      // p0 <- p1
      float go_x=dppf<0xB1>(gB);                        // p0 <- p1's o
      Cc=__builtin_fmaf(gB,Cc,gA*gg_x);                 // valid on p0 (2L2E*c)
      float rcpC;
      if constexpr (TRANS) rcpC=frcp(1.0f+fexp2(Cc));
      else                 rcpC=fminf(fmaxf(__builtin_fmaf(Cc,-0.25f,0.5f),0.0f),1.0f);
      float rcpC_x=dppf<0xB1>(rcpC);                    // p1 <- p0
      float go_u = p ? gB     : go_x;
      float rc_u = p ? rcpC_x : rcpC;
      h=__builtin_fmaf(-2.0f*go_u, rc_u, go_u);         // h = o*tanh(c)

      if constexpr (LDSQ){ pf0=pf1; pf1=pf2; tk2=tk3; }
    }
  }

  // ---- epilogue: capture h_511 (slot 7), flush final octet ----
  if constexpr (FLUSH){
    float r0=h;
    float r1=dppf<0x122>(h), r2=dppf<0x124>(h), r3=dppf<0x126>(h);
    float r4=dppf<0x128>(h), r5=dppf<0x12A>(h), r6=dppf<0x12C>(h), r7=dppf<0x12E>(h);
    bool cap = (s==7);
    hh[0]=cap?r0:hh[0]; hh[1]=cap?r1:hh[1]; hh[2]=cap?r2:hh[2]; hh[3]=cap?r3:hh[3];
    hh[4]=cap?r4:hh[4]; hh[5]=cap?r5:hh[5]; hh[6]=cap?r6:hh[6]; hh[7]=cap?r7:hh[7];
    float a[5];
    #pragma unroll
    for (int o=0;o<5;++o){ a[o]=bdr[o];
      #pragma unroll
      for (int k=0;k<8;++k) a[o]=__builtin_fmaf(hh[k],Wdc[k][o],a[o]); }
    float m=fmaxf(fmaxf(fmaxf(a[0],a[1]),fmaxf(a[2],a[3])),a[4]);
    m=fmaxf(m, dppf<0xB1>(m));
    float e0=fexp2(a[0]-m), e1=fexp2(a[1]-m), e2=fexp2(a[2]-m),
          e3=fexp2(a[3]-m), e4=fexp2(a[4]-m);
    float sm=((e0+e1)+(e2+e3))+e4;
    float r=frcp(sm + dppf<0xB1>(sm));
    outp[0]=e0*r; outp[1]=e1*r; outp[2]=e2*r; outp[3]=e3*r; outp[4]=e4*r;
  }

  // keep recurrence state live for ablated variants (V0 overwrites later)
  if constexpr (V!=0){
    out[(size_t)blockIdx.x*64 + L] = h + Cc;
  }
}

// ---------------------------------------------------------------------------
// Launch: 5 ablation dispatches + control (last, real output).
// inputs: 0 tokens 1 emb 2 W 3 U 4 b 5 Wd 6 bd ; out f32 B*T*10.
// d_ws: 12800 B for the pre-scaled embW table (rewritten every call).
// ---------------------------------------------------------------------------
extern "C" void kernel_launch(void* const* d_in, const int* in_sizes, int n_in,
                              void* d_out, int out_size, void* d_ws, size_t ws_size,
                              hipStream_t stream) {
  const int*   tokens = (const int*)d_in[0];
  const float* emb    = (const float*)d_in[1];
  const float* W      = (const float*)d_in[2];
  const float* U      = (const float*)d_in[3];
  const float* b      = (const float*)d_in[4];
  const float* Wd     = (const float*)d_in[5];
  const float* bd     = (const float*)d_in[6];
  float* outp = (float*)d_out;
  float* embw = (float*)d_ws;

  embw_kernel<<<dim3(VOCABN), dim3(32), 0, stream>>>(emb, W, b, embw);
  lstm_ab<1><<<dim3(BATCHN/4), dim3(64), 0, stream>>>(tokens, embw, U, Wd, bd, outp); // no-LDS
  lstm_ab<2><<<dim3(BATCHN/4), dim3(64), 0, stream>>>(tokens, embw, U, Wd, bd, outp); // no-trans
  lstm_ab<3><<<dim3(BATCHN/4), dim3(64), 0, stream>>>(tokens, embw, U, Wd, bd, outp); // no-flush
  lstm_ab<4><<<dim3(BATCHN/4), dim3(64), 0, stream>>>(tokens, embw, U, Wd, bd, outp); // skeleton
  lstm_ab<0><<<dim3(BATCHN/4), dim3(64), 0, stream>>>(tokens, embw, U, Wd, bd, outp); // CONTROL
}